// Round 2
// baseline (117.630 us; speedup 1.0000x reference)
//
#include <hip/hip_runtime.h>

typedef float f4 __attribute__((ext_vector_type(4)));

#define BB    2
#define DDIM  1024
#define LSEQ  8192
#define LC    128
#define TD    16      // channels per block (4 groups)
#define TL    512     // l-extent per block
#define HALO  128
#define ZW    (TL + HALO)   // 640 floats per staged row
#define ZW4   (ZW/4)        // 160 f4 per row

__device__ __forceinline__ int swz(int j) { return j ^ ((j >> 3) & 7); }

// acc += FIR contribution of 4 taps (k4) given window (Av,Bv) = z[.-1], z[.]
#define FMA4(acc, Av, Bv, k4) \
    acc[0] += k4[0]*Bv[0]; acc[0] += k4[1]*Av[3]; acc[0] += k4[2]*Av[2]; acc[0] += k4[3]*Av[1]; \
    acc[1] += k4[0]*Bv[1]; acc[1] += k4[1]*Bv[0]; acc[1] += k4[2]*Av[3]; acc[1] += k4[3]*Av[2]; \
    acc[2] += k4[0]*Bv[2]; acc[2] += k4[1]*Bv[1]; acc[2] += k4[2]*Bv[0]; acc[2] += k4[3]*Av[3]; \
    acc[3] += k4[0]*Bv[3]; acc[3] += k4[1]*Bv[2]; acc[3] += k4[2]*Bv[1]; acc[3] += k4[3]*Bv[0];

__global__ __launch_bounds__(256) void hyena_fir_kernel(
    const float* __restrict__ x1,
    const float* __restrict__ x2,
    const float* __restrict__ v,
    const float* __restrict__ h,
    const float* __restrict__ cb,
    float* __restrict__ out)
{
    __shared__ f4 zbuf[TD][ZW4];   // z tile (+halo), XOR-swizzled; reused for output staging
    __shared__ f4 ksh[TD/4][LC/4]; // decay filters for the 4 groups (broadcast reads)

    const int t  = threadIdx.x;
    const int d0 = blockIdx.x * TD;
    const int l0 = blockIdx.y * TL;
    const int b  = blockIdx.z;

    // --- build k[g,m] = h[g,m] * exp(-10^(2g/255) * m/127) for our 4 groups ---
    for (int i = t; i < (TD/4)*LC; i += 256) {
        const int gl = i >> 7;
        const int m  = i & (LC-1);
        const int g  = (d0 >> 2) + gl;
        const float dd = __expf((float)g * (2.0f/255.0f) * 2.302585092994046f); // 10^(2g/255)
        ((float*)&ksh[gl][0])[m] = h[g*LC + m] * __expf(-dd * (float)m * (1.0f/127.0f));
    }

    // --- stage z = x2*v for l in [l0-HALO, l0+TL), swizzled, zeros before l=0 ---
    for (int idx = t; idx < TD*ZW4; idx += 256) {
        const int r  = idx / ZW4;
        const int c4 = idx - r*ZW4;
        const int gl = l0 - HALO + c4*4;
        const size_t rb = ((size_t)(b*DDIM + d0 + r)) * LSEQ;
        f4 z = {0.f,0.f,0.f,0.f};
        if (gl >= 0) {
            f4 a = *(const f4*)(x2 + rb + gl);
            f4 w = *(const f4*)(v  + rb + gl);
            z = a * w;
        }
        zbuf[r][swz(c4)] = z;
    }
    __syncthreads();

    // --- FIR: wave owns 4 rows (one group). Pass p: rows 4w+2p + (lane>>5),
    //     32 lanes per row, each lane 16 consecutive l's via a 5-f4 ring. ---
    const int wave = t >> 6, lane = t & 63;
    const f4* __restrict__ kk = &ksh[wave][0];

    for (int p = 0; p < 2; ++p) {
        const int row = wave*4 + p*2 + (lane >> 5);
        const int i32 = lane & 31;
        const int lb  = i32 * 16;           // output l_local base
        const int S   = i32*4 + HALO/4;     // f4 index of z[lb] (logical)
        const f4* __restrict__ zr = &zbuf[row][0];

        // issue x1 loads early (hide latency under the FIR loop)
        const size_t rbase = ((size_t)(b*DDIM + d0 + row)) * LSEQ + l0 + lb;
        const f4 xv0 = *(const f4*)(x1 + rbase + 0);
        const f4 xv1 = *(const f4*)(x1 + rbase + 4);
        const f4 xv2 = *(const f4*)(x1 + rbase + 8);
        const f4 xv3 = *(const f4*)(x1 + rbase + 12);
        const float bd = cb[d0 + row];

        // ring preload: r0..r4 = z[S-1 .. S+3] (f4 units, logical)
        f4 r0 = zr[swz(S-1)];
        f4 r1 = zr[swz(S+0)];
        f4 r2 = zr[swz(S+1)];
        f4 r3 = zr[swz(S+2)];
        f4 r4 = zr[swz(S+3)];
        const f4 zs0 = r1, zs1 = r2, zs2 = r3, zs3 = r4;  // z at output positions

        f4 a0 = {0.f,0.f,0.f,0.f}, a1 = a0, a2 = a0, a3 = a0;

        #pragma unroll
        for (int mc = 0; mc < 32; ++mc) {   // taps m = 4*mc + mm
            const f4 k4 = kk[mc];           // broadcast (whole wave shares one filter)
            FMA4(a0, r0, r1, k4);
            FMA4(a1, r1, r2, k4);
            FMA4(a2, r2, r3, k4);
            FMA4(a3, r3, r4, k4);
            if (mc < 31) {                  // slide window down by one f4
                const f4 nn = zr[swz(S - mc - 2)];
                r4 = r3; r3 = r2; r2 = r1; r1 = r0; r0 = nn;
            }
        }

        // epilogue: bias term, post-gate by x1, stage back (swizzled, logical j = l>>2)
        f4 o0, o1, o2, o3;
        o0[0]=(a0[0]+zs0[0]*bd)*xv0[0]; o0[1]=(a0[1]+zs0[1]*bd)*xv0[1]; o0[2]=(a0[2]+zs0[2]*bd)*xv0[2]; o0[3]=(a0[3]+zs0[3]*bd)*xv0[3];
        o1[0]=(a1[0]+zs1[0]*bd)*xv1[0]; o1[1]=(a1[1]+zs1[1]*bd)*xv1[1]; o1[2]=(a1[2]+zs1[2]*bd)*xv1[2]; o1[3]=(a1[3]+zs1[3]*bd)*xv1[3];
        o2[0]=(a2[0]+zs2[0]*bd)*xv2[0]; o2[1]=(a2[1]+zs2[1]*bd)*xv2[1]; o2[2]=(a2[2]+zs2[2]*bd)*xv2[2]; o2[3]=(a2[3]+zs2[3]*bd)*xv2[3];
        o3[0]=(a3[0]+zs3[0]*bd)*xv3[0]; o3[1]=(a3[1]+zs3[1]*bd)*xv3[1]; o3[2]=(a3[2]+zs3[2]*bd)*xv3[2]; o3[3]=(a3[3]+zs3[3]*bd)*xv3[3];
        const int jb = lb >> 2;
        zbuf[row][swz(jb+0)] = o0;
        zbuf[row][swz(jb+1)] = o1;
        zbuf[row][swz(jb+2)] = o2;
        zbuf[row][swz(jb+3)] = o3;
    }
    __syncthreads();

    // --- transposed write-out: full 64B lines at out[b, l0+l, d0..d0+15] ---
    const int q = t & 3, lidx = t >> 2;
    for (int i = 0; i < 8; ++i) {
        const int l = lidx + i*64;
        const int pj = swz(l >> 2), e = l & 3;
        f4 o;
        o[0] = ((const float*)&zbuf[q*4+0][0])[pj*4+e];
        o[1] = ((const float*)&zbuf[q*4+1][0])[pj*4+e];
        o[2] = ((const float*)&zbuf[q*4+2][0])[pj*4+e];
        o[3] = ((const float*)&zbuf[q*4+3][0])[pj*4+e];
        *(f4*)(out + ((size_t)b*LSEQ + l0 + l)*DDIM + d0 + q*4) = o;
    }
}

extern "C" void kernel_launch(void* const* d_in, const int* in_sizes, int n_in,
                              void* d_out, int out_size, void* d_ws, size_t ws_size,
                              hipStream_t stream) {
    const float* x1 = (const float*)d_in[0];
    const float* x2 = (const float*)d_in[1];
    const float* v  = (const float*)d_in[2];
    const float* h  = (const float*)d_in[3];
    const float* cb = (const float*)d_in[4];
    float* out = (float*)d_out;
    dim3 grid(DDIM/TD, LSEQ/TL, BB);
    hipLaunchKernelGGL(hyena_fir_kernel, grid, dim3(256), 0, stream,
                       x1, x2, v, h, cb, out);
}

// Round 3
// 82.746 us; speedup vs baseline: 1.4216x; 1.4216x over previous
//
#include <hip/hip_runtime.h>

typedef float f4 __attribute__((ext_vector_type(4)));

#define BB    2
#define DDIM  1024
#define LSEQ  8192
#define LC    128
#define TD    16      // channels per block (4 groups, 1 group per wave)
#define TL    512     // l-extent per block
#define HALO  128
#define ZW4   ((TL + HALO) / 4)   // 160 f4 per row

// bank-quad spreading swizzle on f4 index: lanes access j = 4*i + c, so mix
// (j>>2)&7 into the low 3 bits. Bijective within each 8-block, stays in range.
__device__ __forceinline__ int jsw(int j) { return j ^ ((j >> 2) & 7); }

// acc += 4-tap FIR contribution, window (Av,Bv) = z[.-1], z[.]; kv wave-uniform (SGPR)
#define FMA4(acc, Av, Bv, kv) \
    acc[0] += kv[0]*Bv[0]; acc[0] += kv[1]*Av[3]; acc[0] += kv[2]*Av[2]; acc[0] += kv[3]*Av[1]; \
    acc[1] += kv[0]*Bv[1]; acc[1] += kv[1]*Bv[0]; acc[1] += kv[2]*Av[3]; acc[1] += kv[3]*Av[2]; \
    acc[2] += kv[0]*Bv[2]; acc[2] += kv[1]*Bv[1]; acc[2] += kv[2]*Bv[0]; acc[2] += kv[3]*Av[3]; \
    acc[3] += kv[0]*Bv[3]; acc[3] += kv[1]*Bv[2]; acc[3] += kv[2]*Bv[1]; acc[3] += kv[3]*Bv[0];

__global__ __launch_bounds__(256) void build_k_kernel(
    const float* __restrict__ h, float* __restrict__ kbuf)
{
    const int i = blockIdx.x * 256 + threadIdx.x;   // 256*128 = 32768
    const int g = i >> 7, m = i & (LC - 1);
    const float dd = __expf((float)g * (2.0f/255.0f) * 2.302585092994046f); // 10^(2g/255)
    kbuf[i] = h[i] * __expf(-dd * (float)m * (1.0f/127.0f));
}

template<bool GK>
__global__ __launch_bounds__(256, 4) void hyena_fir_kernel(
    const float* __restrict__ x1,
    const float* __restrict__ x2,
    const float* __restrict__ v,
    const float* __restrict__ hsrc,
    const float* __restrict__ cb,
    const float* __restrict__ kbuf,
    float* __restrict__ out)
{
    __shared__ f4 zbuf[TD][ZW4];                  // 40 KB: z tile (+halo), swizzled; reused for output
    __shared__ float kshared[GK ? 4 : 4*LC];      // fallback only

    const int t  = threadIdx.x;
    const int d0 = blockIdx.x * TD;
    const int l0 = blockIdx.y * TL;
    const int b  = blockIdx.z;
    const int wave = t >> 6, lane = t & 63;

    if constexpr (!GK) {
        for (int i = t; i < 4*LC; i += 256) {
            const int gl = i >> 7, m = i & (LC-1);
            const int g  = (d0 >> 2) + gl;
            const float dd = __expf((float)g * (2.0f/255.0f) * 2.302585092994046f);
            kshared[i] = hsrc[g*LC + m] * __expf(-dd * (float)m * (1.0f/127.0f));
        }
    }

    // --- stage z = x2*v for l in [l0-HALO, l0+TL), swizzled, zeros before l=0 ---
    for (int idx = t; idx < TD*ZW4; idx += 256) {
        const int r  = idx / ZW4;
        const int c4 = idx - r*ZW4;
        const int gl = l0 - HALO + c4*4;
        const size_t rb = ((size_t)(b*DDIM + d0 + r)) * LSEQ;
        f4 z = {0.f,0.f,0.f,0.f};
        if (gl >= 0) {
            f4 a = *(const f4*)(x2 + rb + gl);
            f4 w = *(const f4*)(v  + rb + gl);
            z = a * w;
        }
        zbuf[r][jsw(c4)] = z;
    }
    __syncthreads();

    // k pointer: wave-uniform (whole wave = one group) -> scalar loads
    const int goff = __builtin_amdgcn_readfirstlane(((d0 >> 2) + wave) * LC);
    const float* __restrict__ kg = kbuf + goff;
    const f4* __restrict__ kshv = (const f4*)&kshared[(t >> 6) * LC];

    // --- FIR: wave owns rows 4w..4w+3. Pass p: rows 4w+2p+(lane>>5),
    //     32 lanes/row, 16 consecutive l's per lane via a 5-f4 register ring ---
    for (int p = 0; p < 2; ++p) {
        const int row = wave*4 + p*2 + (lane >> 5);
        const int i32 = lane & 31;
        const int S   = i32*4 + HALO/4;           // logical f4 index of first output
        const f4* __restrict__ zr = &zbuf[row][0];

        // x1 loads issued early; consumed at epilogue
        const size_t rbase = ((size_t)(b*DDIM + d0 + row)) * LSEQ + l0 + i32*16;
        const f4 xv0 = *(const f4*)(x1 + rbase + 0);
        const f4 xv1 = *(const f4*)(x1 + rbase + 4);
        const f4 xv2 = *(const f4*)(x1 + rbase + 8);
        const f4 xv3 = *(const f4*)(x1 + rbase + 12);
        const float bd = cb[d0 + row];

        f4 r0 = zr[jsw(S-1)];
        f4 r1 = zr[jsw(S+0)];
        f4 r2 = zr[jsw(S+1)];
        f4 r3 = zr[jsw(S+2)];
        f4 r4 = zr[jsw(S+3)];

        f4 a0 = {0.f,0.f,0.f,0.f}, a1 = a0, a2 = a0, a3 = a0;

        #pragma unroll
        for (int mc = 0; mc < 32; ++mc) {
            f4 kv;
            if constexpr (GK) kv = *(const f4*)(kg + 4*mc);   // s_load_dwordx4 (SGPR)
            else              kv = kshv[mc];                  // broadcast ds_read
            FMA4(a0, r0, r1, kv);
            FMA4(a1, r1, r2, kv);
            FMA4(a2, r2, r3, kv);
            FMA4(a3, r3, r4, kv);
            if (mc < 31) {
                const f4 nn = zr[jsw(S - mc - 2)];
                r4 = r3; r3 = r2; r2 = r1; r1 = r0; r0 = nn;
            }
        }

        // epilogue: re-read z at output positions (frees 16 regs during FIR)
        const f4 zs0 = zr[jsw(S+0)];
        const f4 zs1 = zr[jsw(S+1)];
        const f4 zs2 = zr[jsw(S+2)];
        const f4 zs3 = zr[jsw(S+3)];

        f4 o0, o1, o2, o3;
        o0[0]=(a0[0]+zs0[0]*bd)*xv0[0]; o0[1]=(a0[1]+zs0[1]*bd)*xv0[1]; o0[2]=(a0[2]+zs0[2]*bd)*xv0[2]; o0[3]=(a0[3]+zs0[3]*bd)*xv0[3];
        o1[0]=(a1[0]+zs1[0]*bd)*xv1[0]; o1[1]=(a1[1]+zs1[1]*bd)*xv1[1]; o1[2]=(a1[2]+zs1[2]*bd)*xv1[2]; o1[3]=(a1[3]+zs1[3]*bd)*xv1[3];
        o2[0]=(a2[0]+zs2[0]*bd)*xv2[0]; o2[1]=(a2[1]+zs2[1]*bd)*xv2[1]; o2[2]=(a2[2]+zs2[2]*bd)*xv2[2]; o2[3]=(a2[3]+zs2[3]*bd)*xv2[3];
        o3[0]=(a3[0]+zs3[0]*bd)*xv3[0]; o3[1]=(a3[1]+zs3[1]*bd)*xv3[1]; o3[2]=(a3[2]+zs3[2]*bd)*xv3[2]; o3[3]=(a3[3]+zs3[3]*bd)*xv3[3];

        const int jb = i32*4;
        zbuf[row][jsw(jb+0)] = o0;
        zbuf[row][jsw(jb+1)] = o1;
        zbuf[row][jsw(jb+2)] = o2;
        zbuf[row][jsw(jb+3)] = o3;
    }
    __syncthreads();

    // --- transposed write-out: full 64B lines at out[b, l0+l, d0..d0+15] ---
    const int q = t & 3, lidx = t >> 2;
    for (int i = 0; i < 8; ++i) {
        const int l = lidx + i*64;
        const int pj = jsw(l >> 2), e = l & 3;
        f4 o;
        o[0] = ((const float*)&zbuf[q*4+0][0])[pj*4+e];
        o[1] = ((const float*)&zbuf[q*4+1][0])[pj*4+e];
        o[2] = ((const float*)&zbuf[q*4+2][0])[pj*4+e];
        o[3] = ((const float*)&zbuf[q*4+3][0])[pj*4+e];
        *(f4*)(out + ((size_t)b*LSEQ + l0 + l)*DDIM + d0 + q*4) = o;
    }
}

extern "C" void kernel_launch(void* const* d_in, const int* in_sizes, int n_in,
                              void* d_out, int out_size, void* d_ws, size_t ws_size,
                              hipStream_t stream) {
    const float* x1 = (const float*)d_in[0];
    const float* x2 = (const float*)d_in[1];
    const float* v  = (const float*)d_in[2];
    const float* h  = (const float*)d_in[3];
    const float* cb = (const float*)d_in[4];
    float* out = (float*)d_out;
    dim3 grid(DDIM/TD, LSEQ/TL, BB);

    if (ws_size >= (size_t)(256 * LC * sizeof(float))) {
        float* kbuf = (float*)d_ws;
        hipLaunchKernelGGL(build_k_kernel, dim3(128), dim3(256), 0, stream, h, kbuf);
        hipLaunchKernelGGL((hyena_fir_kernel<true>), grid, dim3(256), 0, stream,
                           x1, x2, v, h, cb, kbuf, out);
    } else {
        hipLaunchKernelGGL((hyena_fir_kernel<false>), grid, dim3(256), 0, stream,
                           x1, x2, v, h, cb, (const float*)nullptr, out);
    }
}

// Round 4
// 67.682 us; speedup vs baseline: 1.7380x; 1.2226x over previous
//
#include <hip/hip_runtime.h>

typedef float f4  __attribute__((ext_vector_type(4)));
typedef short s8v __attribute__((ext_vector_type(8)));

#define BB    2
#define DDIM  1024
#define LSEQ  8192
#define LC    128
#define TD    16      // channels per block = 4 groups, 1 group per wave
#define TL    512     // l-extent per block
#define HALO  128
#define ZSTR  648     // bf16 row stride: 640 data + 8 pad (stride ≡ 1 mod 8 in 16B units)
#define KSTR  176     // padded filter row: index = m + KOFF, m ∈ [-16, 160)
#define KOFF  16

// round-to-nearest-even fp32 -> bf16, packed pair (lo in bits 0-15)
__device__ __forceinline__ unsigned bf16pk(float lo, float hi) {
    unsigned a = __float_as_uint(lo), b = __float_as_uint(hi);
    a = (a + 0x7FFFu + ((a >> 16) & 1u)) >> 16;
    b = (b + 0x7FFFu + ((b >> 16) & 1u));
    return (a & 0xFFFFu) | (b & 0xFFFF0000u);
}

union U8 { s8v s; unsigned u[4]; };

__global__ __launch_bounds__(256, 4) void hyena_mfma_kernel(
    const float* __restrict__ x1,
    const float* __restrict__ x2,
    const float* __restrict__ v,
    const float* __restrict__ h,
    const float* __restrict__ cb,
    float* __restrict__ out)
{
    __shared__ union SM {
        struct { short zb[TD][ZSTR]; float kl[4][KSTR]; } s1;  // phase 1-2: z (bf16) + filters
        f4 ob[TD][TL/4];                                        // phase 3-4: fp32 out staging (32 KB)
    } sm;

    const int t  = threadIdx.x;
    const int d0 = blockIdx.x * TD;
    const int l0 = blockIdx.y * TL;
    const int b  = blockIdx.z;

    // ---- build padded decay filters k[g,m] = h[g,m]*exp(-10^(2g/255)*m/127), 4 groups ----
    for (int idx = t; idx < 4*KSTR; idx += 256) {
        const int gl = idx / KSTR, mi = idx - gl*KSTR;
        const int m  = mi - KOFF;
        float val = 0.f;
        if (m >= 0 && m < LC) {
            const int g = (d0 >> 2) + gl;
            const float dd = __expf((float)g * (2.0f/255.0f) * 2.302585092994046f);
            val = h[g*LC + m] * __expf(-dd * (float)m * (1.0f/127.0f));
        }
        sm.s1.kl[gl][mi] = val;
    }

    // ---- stage z = x2*v as bf16, l ∈ [l0-HALO, l0+TL), zeros before l=0 ----
    #pragma unroll
    for (int it = 0; it < 5; ++it) {
        const int r = t & 15;
        const int s = (t >> 4) + 16*it;          // 80 slots of 8 bf16 per row
        const int gl = l0 - HALO + s*8;
        const size_t rb = ((size_t)(b*DDIM + d0 + r)) * LSEQ;
        U8 zz; zz.s = (s8v){0,0,0,0,0,0,0,0};
        if (gl >= 0) {
            const f4 a0 = *(const f4*)(x2 + rb + gl);
            const f4 a1 = *(const f4*)(x2 + rb + gl + 4);
            const f4 w0 = *(const f4*)(v  + rb + gl);
            const f4 w1 = *(const f4*)(v  + rb + gl + 4);
            const f4 z0 = a0*w0, z1 = a1*w1;
            zz.u[0] = bf16pk(z0[0], z0[1]);
            zz.u[1] = bf16pk(z0[2], z0[3]);
            zz.u[2] = bf16pk(z1[0], z1[1]);
            zz.u[3] = bf16pk(z1[2], z1[3]);
        }
        *(s8v*)&sm.s1.zb[r][s*8] = zz.s;
    }
    __syncthreads();

    // ---- lane geometry (MFMA 16x16x32): j = lane&15 (D col), kb = lane>>4 (k-block) ----
    const int wv = t >> 6, lane = t & 63;
    const int j  = lane & 15, kb = lane >> 4;
    const int qj = j & 3,  cc = j >> 2;          // D col j = (channel cc, l-subtile qj)
    const int row = wv*4 + cc;                   // block-channel this lane's outputs live in

    // ---- A-frags: A_u[i,p] = k_pad[i - p + 16 + 32u], i = lane&15, p = 8*kb + e ----
    s8v afr[5];
    #pragma unroll
    for (int u = 0; u < 5; ++u) {
        const int M0 = j - 8*kb + 16 + 32*u;     // k-index at e=0 (descending in e)
        float kv[8];
        #pragma unroll
        for (int e = 0; e < 8; ++e) kv[e] = sm.s1.kl[wv][M0 - e + KOFF];
        U8 aa;
        aa.u[0] = bf16pk(kv[0], kv[1]);
        aa.u[1] = bf16pk(kv[2], kv[3]);
        aa.u[2] = bf16pk(kv[4], kv[5]);
        aa.u[3] = bf16pk(kv[6], kv[7]);
        afr[u] = aa.s;
    }

    const float bd = cb[d0 + row];
    const size_t chb = ((size_t)(b*DDIM + d0 + row)) * LSEQ + l0;

    // ---- 8 chains: D[i,j] accumulates 5 banded-Toeplitz MFMAs; 64 l × 4 ch per chain ----
    f4 ov[8];
    #pragma unroll
    for (int ci = 0; ci < 8; ++ci) {
        const int L = (4*ci + qj) * 16;          // l-offset of this lane's D column
        f4 acc = {0.f, 0.f, 0.f, 0.f};
        #pragma unroll
        for (int u = 0; u < 5; ++u) {
            int bi = 112 + L + 8*kb - 32*u;      // bf16 index incl. halo; mult of 8
            bi = bi < 0 ? 0 : bi;                // clamped reads pair with A == 0
            const s8v bf = *(const s8v*)&sm.s1.zb[row][bi];
            acc = __builtin_amdgcn_mfma_f32_16x16x32_bf16(afr[u], bf, acc, 0, 0, 0);
        }
        // epilogue: exact fp32 bias via x2*v re-read (L2-hot), gate by x1
        const int lo = L + 4*kb;                 // lane's 4 output l's: lo..lo+3
        const f4 xv = *(const f4*)(x1 + chb + lo);
        const f4 a2 = *(const f4*)(x2 + chb + lo);
        const f4 vv = *(const f4*)(v  + chb + lo);
        f4 o;
        o[0] = (acc[0] + a2[0]*vv[0]*bd) * xv[0];
        o[1] = (acc[1] + a2[1]*vv[1]*bd) * xv[1];
        o[2] = (acc[2] + a2[2]*vv[2]*bd) * xv[2];
        o[3] = (acc[3] + a2[3]*vv[3]*bd) * xv[3];
        ov[ci] = o;
    }
    __syncthreads();                             // z dead; reuse LDS as fp32 out staging

    // ---- stage D results (row-XOR swizzled f4) ----
    #pragma unroll
    for (int ci = 0; ci < 8; ++ci) {
        const int J = (4*ci + qj)*4 + kb;        // f4 col; covers [0,128) exactly once per row
        sm.ob[row][J ^ (row & 7)] = ov[ci];
    }
    __syncthreads();

    // ---- transposed write-out: full 64B lines at out[b, l0+l, d0..d0+15] ----
    const int seg = t & 3;
    #pragma unroll
    for (int it = 0; it < 8; ++it) {
        const int ll = (t >> 2) + it*64;
        const int J = ll >> 2, e = ll & 3;
        f4 o;
        #pragma unroll
        for (int rr = 0; rr < 4; ++rr) {
            const int r2 = seg*4 + rr;
            o[rr] = ((const float*)&sm.ob[r2][J ^ (r2 & 7)])[e];
        }
        *(f4*)(out + ((size_t)b*LSEQ + l0 + ll)*DDIM + d0 + seg*4) = o;
    }
}

extern "C" void kernel_launch(void* const* d_in, const int* in_sizes, int n_in,
                              void* d_out, int out_size, void* d_ws, size_t ws_size,
                              hipStream_t stream) {
    const float* x1 = (const float*)d_in[0];
    const float* x2 = (const float*)d_in[1];
    const float* v  = (const float*)d_in[2];
    const float* h  = (const float*)d_in[3];
    const float* cb = (const float*)d_in[4];
    float* outp = (float*)d_out;
    dim3 grid(DDIM/TD, LSEQ/TL, BB);
    hipLaunchKernelGGL(hyena_mfma_kernel, grid, dim3(256), 0, stream,
                       x1, x2, v, h, cb, outp);
}

// Round 5
// 56.907 us; speedup vs baseline: 2.0670x; 1.1893x over previous
//
#include <hip/hip_runtime.h>

typedef float f4  __attribute__((ext_vector_type(4)));
typedef short s8v __attribute__((ext_vector_type(8)));
typedef short s4v __attribute__((ext_vector_type(4)));

#define BB    2
#define DDIM  1024
#define LSEQ  8192
#define LC    128
#define TD    16      // channels per block = 4 groups, 1 group per wave
#define TL    512     // l-extent per block
#define HALO  128
#define ZSTR  648     // bf16 row stride: 640 data + 8 pad
#define KSTR  176     // padded filter row: index = m + KOFF, m ∈ [-16, 160)
#define KOFF  16

// round-to-nearest-even fp32 -> bf16, packed pair (lo in bits 0-15)
__device__ __forceinline__ unsigned bf16pk(float lo, float hi) {
    unsigned a = __float_as_uint(lo), b = __float_as_uint(hi);
    a = (a + 0x7FFFu + ((a >> 16) & 1u)) >> 16;
    b = (b + 0x7FFFu + ((b >> 16) & 1u));
    return (a & 0xFFFFu) | (b & 0xFFFF0000u);
}
__device__ __forceinline__ float bf2f(short s) {
    return __uint_as_float(((unsigned)(unsigned short)s) << 16);
}

union U8 { s8v s; unsigned u[4]; };

__global__ __launch_bounds__(256, 4) void hyena_mfma_kernel(
    const float* __restrict__ x1,
    const float* __restrict__ x2,
    const float* __restrict__ v,
    const float* __restrict__ h,
    const float* __restrict__ cb,
    float* __restrict__ out)
{
    __shared__ union SM {
        struct { short zb[TD][ZSTR]; float kl[4][KSTR]; } s1;  // z (bf16) + filters
        f4 ob[TD][TL/4];                                        // fp32 out staging (32 KB)
    } sm;

    const int t  = threadIdx.x;
    const int d0 = blockIdx.x * TD;
    const int l0 = blockIdx.y * TL;
    const int b  = blockIdx.z;

    // ---- phase 0: issue ALL z-staging loads into registers (20 x 16B in flight) ----
    const int r = t & 15, sbase = t >> 4;
    const size_t rb = ((size_t)(b*DDIM + d0 + r)) * LSEQ;
    f4 xa0[5], xa1[5], xw0[5], xw1[5];
    #pragma unroll
    for (int it = 0; it < 5; ++it) {
        const int gl = l0 - HALO + (sbase + 16*it)*8;
        if (gl >= 0) {
            xa0[it] = *(const f4*)(x2 + rb + gl);
            xa1[it] = *(const f4*)(x2 + rb + gl + 4);
            xw0[it] = *(const f4*)(v  + rb + gl);
            xw1[it] = *(const f4*)(v  + rb + gl + 4);
        }
    }

    // ---- filter build (h loads + expf VALU) overlaps staging-load latency ----
    for (int idx = t; idx < 4*KSTR; idx += 256) {
        const int gl2 = idx / KSTR, mi = idx - gl2*KSTR;
        const int m  = mi - KOFF;
        float val = 0.f;
        if (m >= 0 && m < LC) {
            const int g = (d0 >> 2) + gl2;
            const float dd = __expf((float)g * (2.0f/255.0f) * 2.302585092994046f);
            val = h[g*LC + m] * __expf(-dd * (float)m * (1.0f/127.0f));
        }
        sm.s1.kl[gl2][mi] = val;
    }

    // ---- convert staged regs -> bf16 z in LDS ----
    #pragma unroll
    for (int it = 0; it < 5; ++it) {
        const int s = sbase + 16*it;
        const int gl = l0 - HALO + s*8;
        U8 zz; zz.s = (s8v){0,0,0,0,0,0,0,0};
        if (gl >= 0) {
            const f4 z0 = xa0[it]*xw0[it], z1 = xa1[it]*xw1[it];
            zz.u[0] = bf16pk(z0[0], z0[1]);
            zz.u[1] = bf16pk(z0[2], z0[3]);
            zz.u[2] = bf16pk(z1[0], z1[1]);
            zz.u[3] = bf16pk(z1[2], z1[3]);
        }
        *(s8v*)&sm.s1.zb[r][s*8] = zz.s;
    }

    // ---- lane geometry (MFMA 16x16x32) + early x1 prefetch (before barrier) ----
    const int wv = t >> 6, lane = t & 63;
    const int j  = lane & 15, kb = lane >> 4;
    const int qj = j & 3,  cc = j >> 2;
    const int row = wv*4 + cc;
    const size_t chb = ((size_t)(b*DDIM + d0 + row)) * LSEQ + l0;
    f4 x1r[8];
    #pragma unroll
    for (int ci = 0; ci < 8; ++ci)
        x1r[ci] = *(const f4*)(x1 + chb + 64*ci + 16*qj + 4*kb);
    const float bd = cb[d0 + row];
    __syncthreads();

    // ---- A-frags: A_u[i,p] = k_pad[i - p + 16 + 32u], i = j, p = 8*kb + e ----
    s8v afr[5];
    #pragma unroll
    for (int u = 0; u < 5; ++u) {
        const int M0 = j - 8*kb + 16 + 32*u;
        float kv[8];
        #pragma unroll
        for (int e = 0; e < 8; ++e) kv[e] = sm.s1.kl[wv][M0 - e + KOFF];
        U8 aa;
        aa.u[0] = bf16pk(kv[0], kv[1]);
        aa.u[1] = bf16pk(kv[2], kv[3]);
        aa.u[2] = bf16pk(kv[4], kv[5]);
        aa.u[3] = bf16pk(kv[6], kv[7]);
        afr[u] = aa.s;
    }

    // ---- 8 chains: 5 banded-Toeplitz MFMAs each; bias from LDS bf16 z; gate x1 ----
    f4 ov[8];
    #pragma unroll
    for (int ci = 0; ci < 8; ++ci) {
        const int L = 64*ci + 16*qj;
        f4 acc = {0.f, 0.f, 0.f, 0.f};
        #pragma unroll
        for (int u = 0; u < 5; ++u) {
            int bi = 112 + L + 8*kb - 32*u;      // zb idx of B_u[p=8kb..], incl. halo
            bi = bi < 0 ? 0 : bi;                // clamped reads pair with A == 0
            const s8v bf = *(const s8v*)&sm.s1.zb[row][bi];
            acc = __builtin_amdgcn_mfma_f32_16x16x32_bf16(afr[u], bf, acc, 0, 0, 0);
        }
        const int lo = L + 4*kb;                 // lane's 4 output l's: lo..lo+3
        const s4v z4 = *(const s4v*)&sm.s1.zb[row][HALO + lo];
        f4 o;
        o[0] = (acc[0] + bf2f(z4[0])*bd) * x1r[ci][0];
        o[1] = (acc[1] + bf2f(z4[1])*bd) * x1r[ci][1];
        o[2] = (acc[2] + bf2f(z4[2])*bd) * x1r[ci][2];
        o[3] = (acc[3] + bf2f(z4[3])*bd) * x1r[ci][3];
        ov[ci] = o;
    }
    __syncthreads();                             // z dead; reuse LDS as fp32 out staging

    // ---- stage D results (row-XOR swizzled f4) ----
    #pragma unroll
    for (int ci = 0; ci < 8; ++ci) {
        const int J = (4*ci + qj)*4 + kb;
        sm.ob[row][J ^ (row & 7)] = ov[ci];
    }
    __syncthreads();

    // ---- transposed write-out: full 64B lines at out[b, l0+l, d0..d0+15] ----
    const int seg = t & 3;
    #pragma unroll
    for (int it = 0; it < 8; ++it) {
        const int ll = (t >> 2) + it*64;
        const int J = ll >> 2, e = ll & 3;
        f4 o;
        #pragma unroll
        for (int rr = 0; rr < 4; ++rr) {
            const int r2 = seg*4 + rr;
            o[rr] = ((const float*)&sm.ob[r2][J ^ (r2 & 7)])[e];
        }
        *(f4*)(out + ((size_t)b*LSEQ + l0 + ll)*DDIM + d0 + seg*4) = o;
    }
}

extern "C" void kernel_launch(void* const* d_in, const int* in_sizes, int n_in,
                              void* d_out, int out_size, void* d_ws, size_t ws_size,
                              hipStream_t stream) {
    const float* x1 = (const float*)d_in[0];
    const float* x2 = (const float*)d_in[1];
    const float* v  = (const float*)d_in[2];
    const float* h  = (const float*)d_in[3];
    const float* cb = (const float*)d_in[4];
    float* outp = (float*)d_out;
    dim3 grid(DDIM/TD, LSEQ/TL, BB);
    hipLaunchKernelGGL(hyena_mfma_kernel, grid, dim3(256), 0, stream,
                       x1, x2, v, h, cb, outp);
}